// Round 18
// baseline (133.722 us; speedup 1.0000x reference)
//
#include <hip/hip_runtime.h>
#include <math.h>

#define TT 1024   // tokens
#define HH 1024   // hidden
#define MM 512    // moe intermediate
#define NE 16     // routed experts (e == NE -> shared expert)
// TOP_K = 2, SCALE = 2.5, NORM_TOPK = true

typedef _Float16 f16;
typedef _Float16 f16x4 __attribute__((ext_vector_type(4)));
typedef _Float16 f16x8 __attribute__((ext_vector_type(8)));
typedef float f32x4 __attribute__((ext_vector_type(4)));

// async global->LDS, 16B/lane, dest = wave-uniform base + lane*16 (linear)
#define GLL(g, l) __builtin_amdgcn_global_load_lds(                         \
    (const __attribute__((address_space(1))) void*)(g),                     \
    (__attribute__((address_space(3))) void*)(l), 16, 0, 0)
#define SB() __builtin_amdgcn_sched_barrier(0)
#define WAITVM(N) { SB(); asm volatile("s_waitcnt vmcnt(" #N ")"); SB(); }
#define BARRIER() __builtin_amdgcn_s_barrier()

// ---------------- pack x -> f16 ----------------
__global__ __launch_bounds__(256) void pack_k(const float* __restrict__ x, f16* __restrict__ xh)
{
    const int i = (blockIdx.x * 256 + threadIdx.x) * 4;
    float4 v = *(const float4*)(x + i);
    f16x4 h = { (f16)v.x, (f16)v.y, (f16)v.z, (f16)v.w };
    *(f16x4*)(xh + i) = h;
}

// ---------------- router ----------------
__global__ __launch_bounds__(256) void router_k(
    const float* __restrict__ x, const float* __restrict__ gate_w,
    int* __restrict__ counts, int* __restrict__ token_list, float* __restrict__ weight_list)
{
    const int wave = threadIdx.x >> 6;
    const int lane = threadIdx.x & 63;
    const int t = (blockIdx.x << 2) + wave;
    const float* xr = x + (size_t)t * HH;
    float xv[16];
#pragma unroll
    for (int i = 0; i < 16; ++i) xv[i] = xr[lane + (i << 6)];
    float sc[NE];
#pragma unroll
    for (int e = 0; e < NE; ++e) {
        const float* gr = gate_w + e * HH;
        float acc = 0.f;
#pragma unroll
        for (int i = 0; i < 16; ++i) acc = fmaf(xv[i], gr[lane + (i << 6)], acc);
#pragma unroll
        for (int off = 32; off > 0; off >>= 1) acc += __shfl_down(acc, off, 64);
        sc[e] = acc;
    }
    if (lane == 0) {
        float l1 = -1e30f, l2 = -1e30f; int i1 = 0, i2 = 0;
#pragma unroll
        for (int e = 0; e < NE; ++e) {
            float v = sc[e];
            if (v > l1) { l2 = l1; i2 = i1; l1 = v; i1 = e; }
            else if (v > l2) { l2 = v; i2 = e; }
        }
        float w1 = 1.f / (1.f + __expf(-l1));
        float w2 = 1.f / (1.f + __expf(-l2));
        const float inv = 2.5f / (w1 + w2 + 1e-20f);
        w1 *= inv; w2 *= inv;
        int s1 = atomicAdd(&counts[i1], 1);
        token_list[i1 * TT + s1] = t;
        weight_list[i1 * TT + s1] = w1;
        int s2 = atomicAdd(&counts[i2], 1);
        token_list[i2 * TT + s2] = t;
        weight_list[i2 * TT + s2] = w2;
    }
}

__global__ void prefix_k(const int* __restrict__ counts, int* __restrict__ offs)
{
    if (threadIdx.x == 0 && blockIdx.x == 0) {
        int acc = 0;
#pragma unroll
        for (int e = 0; e < NE; ++e) { offs[e] = acc; acc += counts[e]; }
        offs[NE] = acc;
    }
}

// ================= fused gate/up =================
// XCD-clustered flat grid. BM=64, BN=32, BK=64.
// A: f16 b128 direct global->VGPR (L2-hot xh), double-buffered reg sets,
//    loaded 1 phase ahead, pinned BEFORE the B GLL issue (sched_barrier) so
//    FIFO retirement order is A(T),B(T),A(T+1),B(T+1),...
// B: fp32 GLL, triple-buffered LDS, counted vmcnt, 2 barriers/phase.
// vmcnt accounting (gu, 4 A-loads + 4 B-GLL per phase):
//   steady phase T outstanding = B(T)4 A(T)4 B(T+1)4 A(T+1)4 B(T+2)4 = 20
//   -> vmcnt(12) retires B(T)+A(T). Phase 0: A0,B0,B1,A1,B2 = 20 -> 12 ok.

#define GU_ALOAD(S, T1) {                                                   \
    aa##S##_[0] = *(const f16x8*)(pa0 + ((T1) << 6));                       \
    aa##S##_[1] = *(const f16x8*)(pa0 + ((T1) << 6) + 32);                  \
    aa##S##_[2] = *(const f16x8*)(pa1 + ((T1) << 6));                       \
    aa##S##_[3] = *(const f16x8*)(pa1 + ((T1) << 6) + 32); }

#define GU_BISSUE(T2, BG, BU) {                                             \
    _Pragma("unroll") for (int i = 0; i < 2; ++i) {                         \
        GLL(pBg[i] + (size_t)((T2) << 6) * MM, &BG[(w << 4) + (i << 3)][0]);\
        GLL(pBu[i] + (size_t)((T2) << 6) * MM, &BU[(w << 4) + (i << 3)][0]); } }

#define GU_COMP(S, BG, BU) {                                                \
    _Pragma("unroll") for (int h = 0; h < 2; ++h) {                         \
        const int kb = (h << 5) + (lg << 3);                                \
        const int bc = (wn + lm) ^ ((lg & 1) << 4);                         \
        f16x8 bg, bu;                                                       \
        _Pragma("unroll") for (int j = 0; j < 8; ++j) {                     \
            bg[j] = (f16)BG[kb + j][bc]; bu[j] = (f16)BU[kb + j][bc]; }     \
        accg[0] = __builtin_amdgcn_mfma_f32_16x16x32_f16(aa##S##_[h],     bg, accg[0], 0, 0, 0); \
        accg[1] = __builtin_amdgcn_mfma_f32_16x16x32_f16(aa##S##_[2 + h], bg, accg[1], 0, 0, 0); \
        accu[0] = __builtin_amdgcn_mfma_f32_16x16x32_f16(aa##S##_[h],     bu, accu[0], 0, 0, 0); \
        accu[1] = __builtin_amdgcn_mfma_f32_16x16x32_f16(aa##S##_[2 + h], bu, accu[1], 0, 0, 0); } }

#define GU_PH(T, SL, SU, BI, BC, VC) {                                      \
    if ((T) + 1 < 16) GU_ALOAD(SL, (T) + 1)                                 \
    SB();                                                                   \
    if ((T) + 2 < 16) GU_BISSUE((T) + 2, Bg##BI, Bu##BI)                    \
    WAITVM(VC) BARRIER();                                                   \
    GU_COMP(SU, Bg##BC, Bu##BC)                                             \
    BARRIER(); }

__global__ __launch_bounds__(256) void gu_k(
    const f16* __restrict__ xh,
    const float* __restrict__ w_gate, const float* __restrict__ w_up,
    const float* __restrict__ ws_gate, const float* __restrict__ ws_up,
    const int* __restrict__ counts, const int* __restrict__ offs,
    const int* __restrict__ token_list, f16* __restrict__ rinter)
{
    const int F = blockIdx.x;
    const int Q = F & 7;
    const int J = F >> 3;
    int e, tile;
    if (J < 512) { e = Q + ((J >> 8) << 3); tile = J & 255; }
    else         { e = NE; tile = (Q << 5) + (J - 512); }
    const int n0 = (tile & 15) << 5;
    const int r0 = (tile >> 4) << 6;

    int cnt, slot0;
    const float *wgp, *wup;
    if (e < NE) {
        cnt = counts[e]; slot0 = offs[e];
        wgp = w_gate + (size_t)e * HH * MM;
        wup = w_up   + (size_t)e * HH * MM;
    } else {
        cnt = TT; slot0 = 2 * TT;
        wgp = ws_gate; wup = ws_up;
    }
    if (r0 >= cnt) return;

    __shared__ float Bg0[64][32], Bg1[64][32], Bg2[64][32];
    __shared__ float Bu0[64][32], Bu1[64][32], Bu2[64][32];
    __shared__ int toks[64];

    const int tid = threadIdx.x;
    if (tid < 64) {
        int i = r0 + tid; if (i >= cnt) i = cnt - 1;
        toks[tid] = (e < NE) ? token_list[e * TT + i] : i;
    }
    __syncthreads();

    const int w = tid >> 6, lane = tid & 63;
    const int lm = lane & 15, lg = lane >> 4;
    const int wm = (w >> 1) << 5, wn = (w & 1) << 4;

    // A rows, lane k-offset folded (r13/r15-verified indexing)
    const f16* pa0 = xh + (size_t)toks[wm + lm]      * HH + (lg << 3);
    const f16* pa1 = xh + (size_t)toks[wm + 16 + lm] * HH + (lg << 3);
    // B source (r12-verified pre-swizzle)
    const float* pBg[2]; const float* pBu[2];
#pragma unroll
    for (int i = 0; i < 2; ++i) {
        int kr = (w << 4) + (i << 3) + (lane >> 3);
        int sg = 4 * ((lane & 7) ^ ((i & 1) << 2));
        pBg[i] = wgp + (size_t)kr * MM + n0 + sg;
        pBu[i] = wup + (size_t)kr * MM + n0 + sg;
    }

    f32x4 accg[2] = {}, accu[2] = {};
    f16x8 aa0_[4], aa1_[4];

    GU_ALOAD(0, 0)
    SB();
    GU_BISSUE(0, Bg0, Bu0)
    GU_BISSUE(1, Bg1, Bu1)

    GU_PH(0, 1, 0, 2, 0, 12)   GU_PH(1, 0, 1, 0, 1, 12)
    GU_PH(2, 1, 0, 1, 2, 12)   GU_PH(3, 0, 1, 2, 0, 12)
    GU_PH(4, 1, 0, 0, 1, 12)   GU_PH(5, 0, 1, 1, 2, 12)
    GU_PH(6, 1, 0, 2, 0, 12)   GU_PH(7, 0, 1, 0, 1, 12)
    GU_PH(8, 1, 0, 1, 2, 12)   GU_PH(9, 0, 1, 2, 0, 12)
    GU_PH(10, 1, 0, 0, 1, 12)  GU_PH(11, 0, 1, 1, 2, 12)
    GU_PH(12, 1, 0, 2, 0, 12)  GU_PH(13, 0, 1, 0, 1, 12)
    GU_PH(14, 1, 0, 0, 2, 12)  GU_PH(15, 0, 1, 0, 0, 0)

    // epilogue: silu(g)*u -> f16; C/D: col=lane&15, row=(lane>>4)*4+reg
#pragma unroll
    for (int fi = 0; fi < 2; ++fi)
#pragma unroll
        for (int rr = 0; rr < 4; ++rr) {
            const int m = wm + (fi << 4) + (lg << 2) + rr;
            if (r0 + m < cnt) {
                float g = (fi ? accg[1] : accg[0])[rr];
                float u = (fi ? accu[1] : accu[0])[rr];
                float s = g / (1.f + __expf(-g));
                rinter[(size_t)(slot0 + r0 + m) * MM + n0 + wn + lm] = (f16)(s * u);
            }
        }
}

// ================= down: out[token] += weight * (rinter @ Wd) =================
// Same A-direct structure. vmcnt accounting (4 A-loads + 2 B-GLL per phase):
//   phase 0 outstanding = A0(4) B0(2) B1(2) A1(4) B2(2) = 14 -> vmcnt(8)
//   retires A0+B0 (r17's vmcnt(12) here left B0 in flight -> the race).
//   steady T>=1: B(T)2 A(T)4 B(T+1)2 A(T+1)4 B(T+2)2 = 14 -> vmcnt(12)
//   retires exactly B(T).

#define DN_ALOAD(S, T1) {                                                   \
    ad##S##_[0] = *(const f16x8*)(pa0 + ((T1) << 6));                       \
    ad##S##_[1] = *(const f16x8*)(pa0 + ((T1) << 6) + 32);                  \
    ad##S##_[2] = *(const f16x8*)(pa1 + ((T1) << 6));                       \
    ad##S##_[3] = *(const f16x8*)(pa1 + ((T1) << 6) + 32); }

#define DN_BISSUE(T2, BS) {                                                 \
    _Pragma("unroll") for (int i = 0; i < 2; ++i)                           \
        GLL(pb[i] + (size_t)((T2) << 6) * HH, &BS[(w << 4) + (i << 3)][0]); }

#define DN_COMP(S, BS) {                                                    \
    _Pragma("unroll") for (int h = 0; h < 2; ++h) {                         \
        const int kb = (h << 5) + (lg << 3);                                \
        const int bc = (wn + lm) ^ ((lg & 1) << 4);                         \
        f16x8 bv;                                                           \
        _Pragma("unroll") for (int j = 0; j < 8; ++j) bv[j] = (f16)BS[kb + j][bc]; \
        acc[0] = __builtin_amdgcn_mfma_f32_16x16x32_f16(ad##S##_[h],     bv, acc[0], 0, 0, 0); \
        acc[1] = __builtin_amdgcn_mfma_f32_16x16x32_f16(ad##S##_[2 + h], bv, acc[1], 0, 0, 0); } }

#define DN_PH(T, SL, SU, BI, BC, VC) {                                      \
    if ((T) + 1 < 8) DN_ALOAD(SL, (T) + 1)                                  \
    SB();                                                                   \
    if ((T) + 2 < 8) DN_BISSUE((T) + 2, Bs##BI)                             \
    WAITVM(VC) BARRIER();                                                   \
    DN_COMP(SU, Bs##BC)                                                     \
    BARRIER(); }

__global__ __launch_bounds__(256) void down_k(
    const f16* __restrict__ rinter,
    const float* __restrict__ w_down, const float* __restrict__ ws_down,
    const int* __restrict__ counts, const int* __restrict__ offs,
    const int* __restrict__ token_list, const float* __restrict__ weight_list,
    float* __restrict__ out)
{
    const int F = blockIdx.x;
    const int Q = F & 7;
    const int J = F >> 3;
    int e, tile;
    if (J < 1024) { e = Q + ((J >> 9) << 3); tile = J & 511; }
    else          { e = NE; tile = (Q << 6) + (J - 1024); }
    const int n0 = (tile & 31) << 5;   // of HH
    const int r0 = (tile >> 5) << 6;

    int cnt, slot0; const float* wdp;
    if (e < NE) { cnt = counts[e]; slot0 = offs[e]; wdp = w_down + (size_t)e * MM * HH; }
    else        { cnt = TT; slot0 = 2 * TT; wdp = ws_down; }
    if (r0 >= cnt) return;

    __shared__ float Bs0[64][32], Bs1[64][32], Bs2[64][32];

    const int tid = threadIdx.x;
    const int w = tid >> 6, lane = tid & 63;
    const int lm = lane & 15, lg = lane >> 4;
    const int wm = (w >> 1) << 5, wn = (w & 1) << 4;

    const f16* pa0 = rinter + (size_t)(slot0 + r0 + wm + lm)      * MM + (lg << 3);
    const f16* pa1 = rinter + (size_t)(slot0 + r0 + wm + 16 + lm) * MM + (lg << 3);
    const float* pb[2];
#pragma unroll
    for (int i = 0; i < 2; ++i) {
        int kr = (w << 4) + (i << 3) + (lane >> 3);
        pb[i] = wdp + (size_t)kr * HH + n0 + 4 * ((lane & 7) ^ ((i & 1) << 2));
    }

    f32x4 acc[2] = {};
    f16x8 ad0_[4], ad1_[4];

    DN_ALOAD(0, 0)
    SB();
    DN_BISSUE(0, Bs0)
    DN_BISSUE(1, Bs1)

    DN_PH(0, 1, 0, 2, 0, 8)   DN_PH(1, 0, 1, 0, 1, 12)
    DN_PH(2, 1, 0, 1, 2, 12)  DN_PH(3, 0, 1, 2, 0, 12)
    DN_PH(4, 1, 0, 0, 1, 12)  DN_PH(5, 0, 1, 1, 2, 12)
    DN_PH(6, 1, 0, 0, 0, 8)   DN_PH(7, 0, 1, 0, 1, 0)

#pragma unroll
    for (int fi = 0; fi < 2; ++fi)
#pragma unroll
        for (int rr = 0; rr < 4; ++rr) {
            const int m = wm + (fi << 4) + (lg << 2) + rr;
            const int row = r0 + m;
            if (row < cnt) {
                int t; float wt;
                if (e < NE) { t = token_list[e * TT + row]; wt = weight_list[e * TT + row]; }
                else        { t = row; wt = 1.f; }
                float v = (fi ? acc[1] : acc[0])[rr];
                atomicAdd(&out[(size_t)t * HH + n0 + wn + lm], wt * v);
            }
        }
}

extern "C" void kernel_launch(void* const* d_in, const int* in_sizes, int n_in,
                              void* d_out, int out_size, void* d_ws, size_t ws_size,
                              hipStream_t stream)
{
    const float* x       = (const float*)d_in[0];
    const float* gate_w  = (const float*)d_in[1];
    const float* w_gate  = (const float*)d_in[2];
    const float* w_up    = (const float*)d_in[3];
    const float* w_down  = (const float*)d_in[4];
    const float* ws_gate = (const float*)d_in[5];
    const float* ws_up   = (const float*)d_in[6];
    const float* ws_down = (const float*)d_in[7];
    float* out = (float*)d_out;

    // ws (r16 layout, known-fits): counts[16]|offs[17] (64 ints) |
    // token_list 16K ints | weight_list 16K floats | rinter f16 [3072][512] |
    // xh f16 [1024][1024]
    int* counts = (int*)d_ws;
    int* offs = counts + 16;
    int* token_list = counts + 64;
    float* weight_list = (float*)(counts + 64 + NE * TT);
    f16* rinter = (f16*)(counts + 64 + 2 * NE * TT);
    f16* xh = rinter + (size_t)3072 * MM;

    hipMemsetAsync(counts, 0, 64, stream);
    hipMemsetAsync(out, 0, (size_t)TT * HH * sizeof(float), stream);
    pack_k<<<dim3(TT * HH / 1024), 256, 0, stream>>>(x, xh);
    router_k<<<dim3(TT / 4), 256, 0, stream>>>(x, gate_w, counts, token_list, weight_list);
    prefix_k<<<1, 64, 0, stream>>>(counts, offs);
    gu_k<<<dim3(8 * 544), 256, 0, stream>>>(
        xh, w_gate, w_up, ws_gate, ws_up, counts, offs, token_list, rinter);
    down_k<<<dim3(8 * 1088), 256, 0, stream>>>(
        rinter, w_down, ws_down, counts, offs, token_list, weight_list, out);
}

// Round 19
// 105.770 us; speedup vs baseline: 1.2643x; 1.2643x over previous
//
#include <hip/hip_runtime.h>
#include <math.h>

#define TT 1024   // tokens
#define HH 1024   // hidden
#define MM 512    // moe intermediate
#define NE 16     // routed experts (e == NE -> shared expert)
// TOP_K = 2, SCALE = 2.5, NORM_TOPK = true

typedef _Float16 f16;
typedef _Float16 f16x4 __attribute__((ext_vector_type(4)));
typedef _Float16 f16x8 __attribute__((ext_vector_type(8)));
typedef float f32x4 __attribute__((ext_vector_type(4)));

// async global->LDS, 16B/lane, dest = wave-uniform base + lane*16 (linear)
#define GLL(g, l) __builtin_amdgcn_global_load_lds(                         \
    (const __attribute__((address_space(1))) void*)(g),                     \
    (__attribute__((address_space(3))) void*)(l), 16, 0, 0)
#define SB() __builtin_amdgcn_sched_barrier(0)
#define WAITVM(N) { SB(); asm volatile("s_waitcnt vmcnt(" #N ")"); SB(); }
#define BARRIER() __builtin_amdgcn_s_barrier()

// ---------------- pack x -> f16 ----------------
__global__ __launch_bounds__(256) void pack_k(const float* __restrict__ x, f16* __restrict__ xh)
{
    const int i = (blockIdx.x * 256 + threadIdx.x) * 4;
    float4 v = *(const float4*)(x + i);
    f16x4 h = { (f16)v.x, (f16)v.y, (f16)v.z, (f16)v.w };
    *(f16x4*)(xh + i) = h;
}

// ---------------- router ----------------
__global__ __launch_bounds__(256) void router_k(
    const float* __restrict__ x, const float* __restrict__ gate_w,
    int* __restrict__ counts, int* __restrict__ token_list, float* __restrict__ weight_list)
{
    const int wave = threadIdx.x >> 6;
    const int lane = threadIdx.x & 63;
    const int t = (blockIdx.x << 2) + wave;
    const float* xr = x + (size_t)t * HH;
    float xv[16];
#pragma unroll
    for (int i = 0; i < 16; ++i) xv[i] = xr[lane + (i << 6)];
    float sc[NE];
#pragma unroll
    for (int e = 0; e < NE; ++e) {
        const float* gr = gate_w + e * HH;
        float acc = 0.f;
#pragma unroll
        for (int i = 0; i < 16; ++i) acc = fmaf(xv[i], gr[lane + (i << 6)], acc);
#pragma unroll
        for (int off = 32; off > 0; off >>= 1) acc += __shfl_down(acc, off, 64);
        sc[e] = acc;
    }
    if (lane == 0) {
        float l1 = -1e30f, l2 = -1e30f; int i1 = 0, i2 = 0;
#pragma unroll
        for (int e = 0; e < NE; ++e) {
            float v = sc[e];
            if (v > l1) { l2 = l1; i2 = i1; l1 = v; i1 = e; }
            else if (v > l2) { l2 = v; i2 = e; }
        }
        float w1 = 1.f / (1.f + __expf(-l1));
        float w2 = 1.f / (1.f + __expf(-l2));
        const float inv = 2.5f / (w1 + w2 + 1e-20f);
        w1 *= inv; w2 *= inv;
        int s1 = atomicAdd(&counts[i1], 1);
        token_list[i1 * TT + s1] = t;
        weight_list[i1 * TT + s1] = w1;
        int s2 = atomicAdd(&counts[i2], 1);
        token_list[i2 * TT + s2] = t;
        weight_list[i2 * TT + s2] = w2;
    }
}

__global__ void prefix_k(const int* __restrict__ counts, int* __restrict__ offs)
{
    if (threadIdx.x == 0 && blockIdx.x == 0) {
        int acc = 0;
#pragma unroll
        for (int e = 0; e < NE; ++e) { offs[e] = acc; acc += counts[e]; }
        offs[NE] = acc;
    }
}

// ================= fused gate/up =================
// BM=128, BN=32, BK=32, 512 threads (8 waves: 4m x 2n). Distance-3 / 4-buffer
// GLL pipeline, 2 GLL/wave/phase (1 A + 1 B; waves 0-3 stage Bg, 4-7 Bu).
// vmcnt: steady out = 4 tiles x 2 = 8 -> vmcnt(6) retires tile T. Tail 6/4/2/0.
// A LDS [128][32] f16, unit-swizzle s^(m&3) -> b128 reads at structural min.
// B LDS [32][32] f32, half-swap swizzle by k-row-group parity (r12-verified).

#define GU_ISSUE(KT, AS, BG, BU) {                                          \
    GLL(pA + (size_t)((KT) << 5), &AS[w << 4][0]);                          \
    GLL(pB + (size_t)((KT) << 5) * MM, (w < 4) ? &BG[(w & 3) << 3][0]       \
                                               : &BU[(w & 3) << 3][0]); }

#define GU_COMP(AS, BG, BU) {                                               \
    f16x8 af[2];                                                            \
    _Pragma("unroll") for (int f = 0; f < 2; ++f) {                         \
        const int m = wm + (f << 4) + lm;                                   \
        af[f] = *(const f16x8*)&AS[m][(lg ^ (m & 3)) << 3];                 \
    }                                                                       \
    const int bc = (wn + lm) ^ ((lg & 1) << 4);                             \
    f16x8 bg, bu;                                                           \
    _Pragma("unroll") for (int j = 0; j < 8; ++j) {                         \
        bg[j] = (f16)BG[(lg << 3) + j][bc];                                 \
        bu[j] = (f16)BU[(lg << 3) + j][bc]; }                               \
    accg[0] = __builtin_amdgcn_mfma_f32_16x16x32_f16(af[0], bg, accg[0], 0, 0, 0); \
    accg[1] = __builtin_amdgcn_mfma_f32_16x16x32_f16(af[1], bg, accg[1], 0, 0, 0); \
    accu[0] = __builtin_amdgcn_mfma_f32_16x16x32_f16(af[0], bu, accu[0], 0, 0, 0); \
    accu[1] = __builtin_amdgcn_mfma_f32_16x16x32_f16(af[1], bu, accu[1], 0, 0, 0); }

#define GU_PH(KT, IB, CB, VC) {                                             \
    if ((KT) + 3 < 32) GU_ISSUE((KT) + 3, As##IB, Bg##IB, Bu##IB)           \
    WAITVM(VC) BARRIER();                                                   \
    GU_COMP(As##CB, Bg##CB, Bu##CB)                                         \
    BARRIER(); }

__global__ __launch_bounds__(512) void gu_k(
    const f16* __restrict__ xh,
    const float* __restrict__ w_gate, const float* __restrict__ w_up,
    const float* __restrict__ ws_gate, const float* __restrict__ ws_up,
    const int* __restrict__ counts, const int* __restrict__ offs,
    const int* __restrict__ token_list, f16* __restrict__ rinter)
{
    const int F = blockIdx.x;
    const int Q = F & 7;
    const int J = F >> 3;                // 0..271 per XCD
    int e, n0, r0;
    if (J < 256) {                        // routed: 2 experts x 16n x 8 rowblocks
        e = Q + ((J >> 7) << 3);
        n0 = (J & 15) << 5;
        r0 = ((J & 127) >> 4) << 7;
    } else {                              // shared slice: 16 tiles per XCD
        e = NE;
        int idx = (Q << 4) + (J - 256);   // 0..127
        n0 = (idx & 15) << 5;
        r0 = (idx >> 4) << 7;
    }

    int cnt, slot0;
    const float *wgp, *wup;
    if (e < NE) {
        cnt = counts[e]; slot0 = offs[e];
        wgp = w_gate + (size_t)e * HH * MM;
        wup = w_up   + (size_t)e * HH * MM;
    } else {
        cnt = TT; slot0 = 2 * TT;
        wgp = ws_gate; wup = ws_up;
    }
    if (r0 >= cnt) return;

    __shared__ f16  As0[128][32], As1[128][32], As2[128][32], As3[128][32];
    __shared__ float Bg0[32][32], Bg1[32][32], Bg2[32][32], Bg3[32][32];
    __shared__ float Bu0[32][32], Bu1[32][32], Bu2[32][32], Bu3[32][32];
    __shared__ int toks[128];

    const int tid = threadIdx.x;
    if (tid < 128) {
        int i = r0 + tid; if (i >= cnt) i = cnt - 1;
        toks[tid] = (e < NE) ? token_list[e * TT + i] : i;
    }
    __syncthreads();

    const int w = tid >> 6, lane = tid & 63;
    const int lm = lane & 15, lg = lane >> 4;
    const int wm = (w >> 1) << 5;        // 0,32,64,96
    const int wn = (w & 1) << 4;         // 0,16

    // A GLL source: wave w rows w*16..+15; lane -> row (w<<4)+(lane>>2),
    // dest unit (lane&3); src unit = (lane&3)^(row&3) realizes the swizzle.
    const int arow = (w << 4) + (lane >> 2);
    const f16* pA = xh + (size_t)toks[arow] * HH
                       + (size_t)(((lane & 3) ^ ((lane >> 2) & 3)) << 3);
    // B GLL source: waves 0-3 -> Bg rows, 4-7 -> Bu rows; 8 k-rows per wave.
    const int kr = ((w & 3) << 3) + (lane >> 3);
    const int sg = 4 * ((lane & 7) ^ ((w & 1) << 2));
    const float* pB = ((w < 4) ? wgp : wup) + (size_t)kr * MM + n0 + sg;

    f32x4 accg[2] = {}, accu[2] = {};

    GU_ISSUE(0, As0, Bg0, Bu0)
    GU_ISSUE(1, As1, Bg1, Bu1)
    GU_ISSUE(2, As2, Bg2, Bu2)

#pragma unroll 1
    for (int kt = 0; kt < 28; kt += 4) {
        GU_PH(kt + 0, 3, 0, 6)
        GU_PH(kt + 1, 0, 1, 6)
        GU_PH(kt + 2, 1, 2, 6)
        GU_PH(kt + 3, 2, 3, 6)
    }
    GU_PH(28, 3, 0, 6)                   // issues tile 31
    { WAITVM(4) BARRIER(); GU_COMP(As1, Bg1, Bu1) BARRIER(); }   // 29
    { WAITVM(2) BARRIER(); GU_COMP(As2, Bg2, Bu2) BARRIER(); }   // 30
    { WAITVM(0) BARRIER(); GU_COMP(As3, Bg3, Bu3) BARRIER(); }   // 31

    // epilogue: silu(g)*u -> f16; C/D: col=lane&15, row=(lane>>4)*4+reg
#pragma unroll
    for (int fi = 0; fi < 2; ++fi)
#pragma unroll
        for (int rr = 0; rr < 4; ++rr) {
            const int m = wm + (fi << 4) + (lg << 2) + rr;
            if (r0 + m < cnt) {
                float g = (fi ? accg[1] : accg[0])[rr];
                float u = (fi ? accu[1] : accu[0])[rr];
                float s = g / (1.f + __expf(-g));
                rinter[(size_t)(slot0 + r0 + m) * MM + n0 + wn + lm] = (f16)(s * u);
            }
        }
}

// ================= down (r16-exact): out[token] += weight * (rinter @ Wd) ======
// A f16 GLL [64][64] x3 + B fp32 GLL [64][32] x3, distance-2, 4 GLL/wave/phase,
// vmcnt(8) steady (12 outstanding, retire 4 of tile T).

#define DN_ISSUE(T2, AS, BS) {                                              \
    _Pragma("unroll") for (int i = 0; i < 2; ++i) {                         \
        GLL(pa[i] + ((T2) << 6), &AS[(w << 4) + (i << 3)][0]);              \
        GLL(pb[i] + (size_t)((T2) << 6) * HH, &BS[(w << 4) + (i << 3)][0]); } }

#define DN_COMP(AS, BS) {                                                   \
    _Pragma("unroll") for (int h = 0; h < 2; ++h) {                         \
        const int kb = (h << 5) + (lg << 3);                                \
        const int ko = (h << 2) + lg;                                       \
        f16x8 af[2];                                                        \
        _Pragma("unroll") for (int f = 0; f < 2; ++f) {                     \
            const int m = wm + (f << 4) + lm;                               \
            af[f] = *(const f16x8*)&AS[m][(ko ^ (m & 7)) << 3];             \
        }                                                                   \
        const int bc = (wn + lm) ^ ((lg & 1) << 4);                         \
        f16x8 bv;                                                           \
        _Pragma("unroll") for (int j = 0; j < 8; ++j) bv[j] = (f16)BS[kb + j][bc]; \
        _Pragma("unroll") for (int f = 0; f < 2; ++f)                       \
            acc[f] = __builtin_amdgcn_mfma_f32_16x16x32_f16(af[f], bv, acc[f], 0, 0, 0); } }

#define DN_PHI(T2, AI, BC, VC) { DN_ISSUE(T2, As##AI, Bs##AI)               \
    WAITVM(VC) BARRIER();                                                   \
    DN_COMP(As##BC, Bs##BC) BARRIER(); }
#define DN_PHN(BC, VC) { WAITVM(VC) BARRIER();                              \
    DN_COMP(As##BC, Bs##BC) BARRIER(); }

__global__ __launch_bounds__(256) void down_k(
    const f16* __restrict__ rinter,
    const float* __restrict__ w_down, const float* __restrict__ ws_down,
    const int* __restrict__ counts, const int* __restrict__ offs,
    const int* __restrict__ token_list, const float* __restrict__ weight_list,
    float* __restrict__ out)
{
    const int F = blockIdx.x;
    const int Q = F & 7;
    const int J = F >> 3;
    int e, tile;
    if (J < 1024) { e = Q + ((J >> 9) << 3); tile = J & 511; }
    else          { e = NE; tile = (Q << 6) + (J - 1024); }
    const int n0 = (tile & 31) << 5;   // of HH
    const int r0 = (tile >> 5) << 6;

    int cnt, slot0; const float* wdp;
    if (e < NE) { cnt = counts[e]; slot0 = offs[e]; wdp = w_down + (size_t)e * MM * HH; }
    else        { cnt = TT; slot0 = 2 * TT; wdp = ws_down; }
    if (r0 >= cnt) return;

    __shared__ f16  As0[64][64], As1[64][64], As2[64][64];
    __shared__ float Bs0[64][32], Bs1[64][32], Bs2[64][32];

    const int tid = threadIdx.x;
    const int w = tid >> 6, lane = tid & 63;
    const int lm = lane & 15, lg = lane >> 4;
    const int wm = (w >> 1) << 5, wn = (w & 1) << 4;

    const f16* pa[2];
#pragma unroll
    for (int i = 0; i < 2; ++i) {
        int m = (w << 4) + (i << 3) + (lane >> 3);   // contiguous slots
        pa[i] = rinter + (size_t)(slot0 + r0 + m) * MM + (((lane & 7) ^ (lane >> 3)) << 3);
    }
    const float* pb[2];
#pragma unroll
    for (int i = 0; i < 2; ++i) {
        int kr = (w << 4) + (i << 3) + (lane >> 3);
        pb[i] = wdp + (size_t)kr * HH + n0 + 4 * ((lane & 7) ^ ((i & 1) << 2));
    }

    f32x4 acc[2] = {};

    DN_ISSUE(0, As0, Bs0)
    DN_ISSUE(1, As1, Bs1)

    DN_PHI(2,2,0,8) DN_PHI(3,0,1,8) DN_PHI(4,1,2,8)
    DN_PHI(5,2,0,8) DN_PHI(6,0,1,8) DN_PHI(7,1,2,8)
    DN_PHN(0,4)     DN_PHN(1,0)

#pragma unroll
    for (int fi = 0; fi < 2; ++fi)
#pragma unroll
        for (int rr = 0; rr < 4; ++rr) {
            const int m = wm + (fi << 4) + (lg << 2) + rr;
            const int row = r0 + m;
            if (row < cnt) {
                int t; float wt;
                if (e < NE) { t = token_list[e * TT + row]; wt = weight_list[e * TT + row]; }
                else        { t = row; wt = 1.f; }
                float v = (fi ? acc[1] : acc[0])[rr];
                atomicAdd(&out[(size_t)t * HH + n0 + wn + lm], wt * v);
            }
        }
}

extern "C" void kernel_launch(void* const* d_in, const int* in_sizes, int n_in,
                              void* d_out, int out_size, void* d_ws, size_t ws_size,
                              hipStream_t stream)
{
    const float* x       = (const float*)d_in[0];
    const float* gate_w  = (const float*)d_in[1];
    const float* w_gate  = (const float*)d_in[2];
    const float* w_up    = (const float*)d_in[3];
    const float* w_down  = (const float*)d_in[4];
    const float* ws_gate = (const float*)d_in[5];
    const float* ws_up   = (const float*)d_in[6];
    const float* ws_down = (const float*)d_in[7];
    float* out = (float*)d_out;

    // ws (r16 layout): counts[16]|offs[17] (64 ints) | token_list 16K ints |
    // weight_list 16K floats | rinter f16 [3072][512] | xh f16 [1024][1024]
    int* counts = (int*)d_ws;
    int* offs = counts + 16;
    int* token_list = counts + 64;
    float* weight_list = (float*)(counts + 64 + NE * TT);
    f16* rinter = (f16*)(counts + 64 + 2 * NE * TT);
    f16* xh = rinter + (size_t)3072 * MM;

    hipMemsetAsync(counts, 0, 64, stream);
    hipMemsetAsync(out, 0, (size_t)TT * HH * sizeof(float), stream);
    pack_k<<<dim3(TT * HH / 1024), 256, 0, stream>>>(x, xh);
    router_k<<<dim3(TT / 4), 256, 0, stream>>>(x, gate_w, counts, token_list, weight_list);
    prefix_k<<<1, 64, 0, stream>>>(counts, offs);
    gu_k<<<dim3(8 * 272), 512, 0, stream>>>(
        xh, w_gate, w_up, ws_gate, ws_up, counts, offs, token_list, rinter);
    down_k<<<dim3(8 * 1088), 256, 0, stream>>>(
        rinter, w_down, ws_down, counts, offs, token_list, weight_list, out);
}